// Round 6
// baseline (150.794 us; speedup 1.0000x reference)
//
#include <hip/hip_runtime.h>

// Correction_Module_dense_checksum: ABFT 2x2 block checksum verify + correct.
// A: (8192, 64) f32, B: (8192, 64) f32, C_faulty: (8192, 8192) f32 -> out f32.
// check[i][j] = (B[2i]+B[2i+1]) . (A[2j]+A[2j+1]); actual = 2x2 block sum of C.
// Flag iff |actual - check| > ATOL + RTOL*|check|; flagged blocks recomputed
// as B[r].A[c]. Fault margin ~100 vs tol ~1e-3 -> mask reproduction-robust.
//
// R6: strip-mined pipeline. R4 falsified MLP/occupancy, R5 falsified burst
// length (both 110us, memset on same buffer = 6.8 TB/s). Remaining theory:
// bursty phases — every block paid AC-staging latency + a memory-silent dot
// phase per 64KB of C. Now: block owns 256x256 panel, stages AC once (32KB
// LDS, reused 8x), walks 8 strips of 32 rows; strip s+1's C/BC loads are in
// flight during strip s's dot loop (double-buffered BC in LDS, cvA/cvB in
// regs). Memory issue never sleeps; prologue paid 1024x not 8192x.

constexpr int   Ddim   = 64;
constexpr int   NCOL   = 8192;
constexpr int   SROWS  = 32;    // rows per strip
constexpr int   NSTRIP = 8;     // strips per block (256 rows)
constexpr int   COLS   = 256;   // cols per block
constexpr float ATOL   = 1e-3f;
constexpr float RTOL   = 1e-4f;

typedef float vfloat4 __attribute__((ext_vector_type(4)));

__device__ __forceinline__ void nt_store4(float* p, float4 v) {
    vfloat4 w = {v.x, v.y, v.z, v.w};
    __builtin_nontemporal_store(w, (vfloat4*)p);
}

__device__ __forceinline__ void recompute2x2(const float* __restrict__ A,
                                             const float* __restrict__ B,
                                             int r0, int c0,
                                             float& e00, float& e01,
                                             float& e10, float& e11)
{
    const float* b0 = B + (size_t)r0 * Ddim;
    const float* b1 = b0 + Ddim;
    const float* a0 = A + (size_t)c0 * Ddim;
    const float* a1 = a0 + Ddim;
    float d00 = 0.f, d01 = 0.f, d10 = 0.f, d11 = 0.f;
    for (int d = 0; d < Ddim; ++d) {
        float bb0 = b0[d], bb1 = b1[d], aa0 = a0[d], aa1 = a1[d];
        d00 += bb0 * aa0;
        d01 += bb0 * aa1;
        d10 += bb1 * aa0;
        d11 += bb1 * aa1;
    }
    e00 = d00; e01 = d01; e10 = d10; e11 = d11;
}

__global__ __launch_bounds__(256, 4)
void correct_kernel(const float* __restrict__ A, const float* __restrict__ B,
                    const float* __restrict__ C, float* __restrict__ out)
{
    __shared__ float ACs[64][128];     // pair-summed A, staged once: 32 KiB
    __shared__ float BCs[2][64][16];   // pair-summed B, double-buffered: 8 KiB

    const int t  = threadIdx.x;
    const int bx = blockIdx.x;         // col panel 0..31 (256 cols)
    const int gy = blockIdx.y;         // row panel 0..31 (256 rows)
    const int w  = t >> 6;             // wave 0..3
    const int l  = t & 63;             // lane

    const int ib = t & 15;             // BC staging: i-block
    const int dh = t >> 4;             // BC staging: d-chunk (4 d's)

    // ---- prologue: AC loads, BC0 loads, C0 loads (in that vmcnt order) ----
    const int jj = t & 127;
    const int q  = t >> 7;
    const float* arow = A + (size_t)(bx * 128 + jj) * 2 * Ddim + q * 32;
    float4 sa0[8], sa1[8];
    #pragma unroll
    for (int i = 0; i < 8; ++i) {
        sa0[i] = *(const float4*)(arow + 4 * i);
        sa1[i] = *(const float4*)(arow + Ddim + 4 * i);
    }
    const float* brow0 = B + (size_t)(gy * 256 + 2 * ib) * Ddim + dh * 4;
    float4 sb0 = *(const float4*)(brow0);
    float4 sb1 = *(const float4*)(brow0 + Ddim);

    const size_t colbase = (size_t)(bx * COLS + 4 * l);
    const size_t rowtop  = (size_t)(gy * 256);
    float4 cvA[8], cvB[8];
    {
        const float* p = C + (rowtop + 8 * w) * NCOL + colbase;
        #pragma unroll
        for (int rr = 0; rr < 8; ++rr)
            cvA[rr] = *(const float4*)(p + (size_t)rr * NCOL);
    }

    // ---- LDS writes (wait staging loads only; C0 stays in flight) ----
    #pragma unroll
    for (int i = 0; i < 8; ++i) {
        const int d0 = q * 32 + 4 * i;
        #pragma unroll
        for (int k = 0; k < 4; ++k)    // banks jj%32, 2 lanes/bank: free
            ACs[d0 + k][jj] = ((const float*)&sa0[i])[k] + ((const float*)&sa1[i])[k];
    }
    #pragma unroll
    for (int k = 0; k < 4; ++k)
        BCs[0][dh * 4 + k][ib] = ((const float*)&sb0)[k] + ((const float*)&sb1)[k];
    __syncthreads();

    // ---- strip loop: process cur strip while next strip's loads fly ----
    // PF issues next-strip BC (first) + C loads; dot hides their latency;
    // barrier's vmcnt(0) drain is then nearly free.
#define STRIP_BODY(CV_CUR, CV_NXT, S, DO_PF)                                     \
    {                                                                            \
        const int s = (S);                                                       \
        float4 nb0, nb1;                                                         \
        if (DO_PF) {                                                             \
            const float* brow = B + (size_t)(gy * 256 + (s + 1) * SROWS          \
                                             + 2 * ib) * Ddim + dh * 4;          \
            nb0 = *(const float4*)(brow);                                        \
            nb1 = *(const float4*)(brow + Ddim);                                 \
            const float* p = C + (rowtop + (s + 1) * SROWS + 8 * w) * NCOL       \
                               + colbase;                                        \
            _Pragma("unroll")                                                    \
            for (int rr = 0; rr < 8; ++rr)                                       \
                CV_NXT[rr] = *(const float4*)(p + (size_t)rr * NCOL);            \
        }                                                                        \
        float acc[4][2];                                                         \
        _Pragma("unroll")                                                        \
        for (int a = 0; a < 4; ++a) { acc[a][0] = 0.f; acc[a][1] = 0.f; }        \
        const float (*bc)[16] = BCs[s & 1];                                      \
        _Pragma("unroll 16")                                                     \
        for (int d = 0; d < 64; ++d) {                                           \
            float4 b4 = *(const float4*)&bc[d][4 * w];    /* wave-uniform */     \
            float2 a2 = *(const float2*)&ACs[d][2 * l];   /* 512B, spread */     \
            const float bv[4] = {b4.x, b4.y, b4.z, b4.w};                        \
            _Pragma("unroll")                                                    \
            for (int a = 0; a < 4; ++a) {                                        \
                acc[a][0] += bv[a] * a2.x;                                       \
                acc[a][1] += bv[a] * a2.y;                                       \
            }                                                                    \
        }                                                                        \
        if (DO_PF) {                                                             \
            _Pragma("unroll")                                                    \
            for (int k = 0; k < 4; ++k)                                          \
                BCs[(s + 1) & 1][dh * 4 + k][ib] =                               \
                    ((const float*)&nb0)[k] + ((const float*)&nb1)[k];           \
        }                                                                        \
        __syncthreads();                                                         \
        const size_t rb = (rowtop + s * SROWS + 8 * w) * (size_t)NCOL + colbase; \
        _Pragma("unroll")                                                        \
        for (int a = 0; a < 4; ++a) {                                            \
            float4 c0 = CV_CUR[2 * a], c1 = CV_CUR[2 * a + 1];                   \
            float s0 = (c0.x + c0.y) + (c1.x + c1.y);                            \
            float s1 = (c0.z + c0.w) + (c1.z + c1.w);                            \
            bool f0 = fabsf(s0 - acc[a][0]) > ATOL + RTOL * fabsf(acc[a][0]);    \
            bool f1 = fabsf(s1 - acc[a][1]) > ATOL + RTOL * fabsf(acc[a][1]);    \
            if (f0 | f1) {                                                       \
                const int r0  = (int)(rowtop) + s * SROWS + 8 * w + 2 * a;       \
                const int c0i = (int)colbase;                                    \
                if (f0) recompute2x2(A, B, r0, c0i,     c0.x, c0.y, c1.x, c1.y); \
                if (f1) recompute2x2(A, B, r0, c0i + 2, c0.z, c0.w, c1.z, c1.w); \
            }                                                                    \
            nt_store4(out + rb + (size_t)(2 * a) * NCOL,     c0);                \
            nt_store4(out + rb + (size_t)(2 * a + 1) * NCOL, c1);                \
        }                                                                        \
    }

    #pragma unroll 1
    for (int sp = 0; sp < 4; ++sp) {
        STRIP_BODY(cvA, cvB, 2 * sp,     true);      // next strip 2sp+1 <= 7
        STRIP_BODY(cvB, cvA, 2 * sp + 1, (sp < 3));  // no prefetch past end
    }
#undef STRIP_BODY
}

extern "C" void kernel_launch(void* const* d_in, const int* in_sizes, int n_in,
                              void* d_out, int out_size, void* d_ws, size_t ws_size,
                              hipStream_t stream) {
    const float* A = (const float*)d_in[0];   // (8192, 64)
    const float* B = (const float*)d_in[1];   // (8192, 64)
    const float* C = (const float*)d_in[2];   // (8192, 8192) faulty
    float* out = (float*)d_out;               // (8192, 8192)
    dim3 grid(NCOL / COLS, NCOL / (SROWS * NSTRIP));   // 32 x 32 = 1024 = 4/CU
    correct_kernel<<<grid, 256, 0, stream>>>(A, B, C, out);
}

// Round 7
// 134.637 us; speedup vs baseline: 1.1200x; 1.1200x over previous
//
#include <hip/hip_runtime.h>

// Correction_Module_dense_checksum: ABFT 2x2 block checksum verify + correct.
// A: (8192, 64) f32, B: (8192, 64) f32, C_faulty: (8192, 8192) f32 -> out f32.
// check[i][j] = (B[2i]+B[2i+1]) . (A[2j]+A[2j+1]); actual = 2x2 block sum of C.
// Flag iff |actual - check| > ATOL + RTOL*|check|; flagged blocks recomputed
// as B[r].A[c]. Fault margin ~100 vs tol ~1e-3 -> mask reproduction-robust.
//
// R7: A/B isolate the nt store. R3/R4/R5 (three different structures) all
// pin at 110us / 3.7 TB/s; R6's pipeline test was corrupted by VGPR spills
// (FETCH/WRITE excess = scratch traffic). The only never-isolated variable
// common to every 110us run is __builtin_nontemporal_store on the 268MB
// write stream; harness memset with REGULAR stores hits 6.8 TB/s on the
// same buffer. This kernel == R5 exactly, with plain float4 stores.

constexpr int   Ddim = 64;
constexpr int   NCOL = 8192;
constexpr int   ROWS = 32;    // tile rows per block
constexpr int   COLS = 256;   // tile cols per block
constexpr float ATOL = 1e-3f;
constexpr float RTOL = 1e-4f;

__device__ __forceinline__ void recompute2x2(const float* __restrict__ A,
                                             const float* __restrict__ B,
                                             int r0, int c0,
                                             float& e00, float& e01,
                                             float& e10, float& e11)
{
    const float* b0 = B + (size_t)r0 * Ddim;
    const float* b1 = b0 + Ddim;
    const float* a0 = A + (size_t)c0 * Ddim;
    const float* a1 = a0 + Ddim;
    float d00 = 0.f, d01 = 0.f, d10 = 0.f, d11 = 0.f;
    for (int d = 0; d < Ddim; ++d) {
        float bb0 = b0[d], bb1 = b1[d], aa0 = a0[d], aa1 = a1[d];
        d00 += bb0 * aa0;
        d01 += bb0 * aa1;
        d10 += bb1 * aa0;
        d11 += bb1 * aa1;
    }
    e00 = d00; e01 = d01; e10 = d10; e11 = d11;
}

__global__ __launch_bounds__(256, 4)
void correct_kernel(const float* __restrict__ A, const float* __restrict__ B,
                    const float* __restrict__ C, float* __restrict__ out)
{
    // [d][j] layout. AC dot-read is 512B/wave = inherent 4 LDS cycles
    // (BW-optimal); BC dot-read is wave-uniform broadcast.
    __shared__ float ACs[64][128];   // pair-summed A for 128 j-blocks, 32 KiB
    __shared__ float BCs[64][16];    // pair-summed B for 16 i-blocks,  4 KiB

    const int t  = threadIdx.x;
    const int bx = blockIdx.x;       // 256-col tile
    const int by = blockIdx.y;       // 32-row strip
    const int w  = t >> 6;           // wave 0..3
    const int l  = t & 63;           // lane

    // ---- staging loads first (they gate the barrier) ----
    // AC: thread covers j-block jj, d-half q (32 d's): 16 float4 from L2.
    const int jj = t & 127;
    const int q  = t >> 7;
    const float* arow = A + (size_t)(bx * 128 + jj) * 2 * Ddim + q * 32;
    float4 sa0[8], sa1[8];
    #pragma unroll
    for (int i = 0; i < 8; ++i) {
        sa0[i] = *(const float4*)(arow + 4 * i);
        sa1[i] = *(const float4*)(arow + Ddim + 4 * i);
    }
    // BC: thread covers i-block ib, d-chunk dh (4 d's): 2 float4.
    const int ib = t & 15;
    const int dh = t >> 4;
    const float* brow = B + (size_t)(by * ROWS + 2 * ib) * Ddim + dh * 4;
    float4 sb0 = *(const float4*)(brow);
    float4 sb1 = *(const float4*)(brow + Ddim);

    // ---- C loads: wave w covers rows 8w..8w+7, lane l cols 4l..4l+3 ----
    // One instr = 64 lanes x 16B = 1 KB contiguous (full tile row).
    const size_t rowbase = (size_t)(by * ROWS + 8 * w) * NCOL
                         + (size_t)(bx * COLS + 4 * l);
    float4 cv[8];
    #pragma unroll
    for (int rr = 0; rr < 8; ++rr)
        cv[rr] = *(const float4*)(C + rowbase + (size_t)rr * NCOL);

    // ---- pair-sum into LDS (waits staging only; cv stays in flight) ----
    #pragma unroll
    for (int i = 0; i < 8; ++i) {
        const int d0 = q * 32 + 4 * i;
        #pragma unroll
        for (int k = 0; k < 4; ++k)   // banks = jj%32, 2 lanes/bank: free
            ACs[d0 + k][jj] = ((const float*)&sa0[i])[k] + ((const float*)&sa1[i])[k];
    }
    #pragma unroll
    for (int k = 0; k < 4; ++k)
        BCs[dh * 4 + k][ib] = ((const float*)&sb0)[k] + ((const float*)&sb1)[k];
    __syncthreads();

    // ---- checksum dots: thread owns i-blocks 4w+a (a=0..3), j-blocks 2l+b --
    float acc[4][2];
    #pragma unroll
    for (int a = 0; a < 4; ++a) { acc[a][0] = 0.f; acc[a][1] = 0.f; }

    #pragma unroll 16
    for (int d = 0; d < 64; ++d) {
        float4 bc = *(const float4*)&BCs[d][4 * w];   // wave-uniform: bcast
        float2 ac = *(const float2*)&ACs[d][2 * l];   // 512B/wave: 4cy, full BW
        const float bcv[4] = {bc.x, bc.y, bc.z, bc.w};
        #pragma unroll
        for (int a = 0; a < 4; ++a) {
            acc[a][0] += bcv[a] * ac.x;
            acc[a][1] += bcv[a] * ac.y;
        }
    }

    // ---- block sums, compare, rare fix, store (REGULAR stores this round) --
    #pragma unroll
    for (int a = 0; a < 4; ++a) {
        float4 c0 = cv[2 * a], c1 = cv[2 * a + 1];
        float s0 = (c0.x + c0.y) + (c1.x + c1.y);
        float s1 = (c0.z + c0.w) + (c1.z + c1.w);
        bool f0 = fabsf(s0 - acc[a][0]) > ATOL + RTOL * fabsf(acc[a][0]);
        bool f1 = fabsf(s1 - acc[a][1]) > ATOL + RTOL * fabsf(acc[a][1]);
        if (f0 | f1) {               // ~670 of 16.7M blocks: divergence fine
            const int r0 = by * ROWS + 8 * w + 2 * a;
            const int c0i = bx * COLS + 4 * l;
            if (f0) recompute2x2(A, B, r0, c0i,     c0.x, c0.y, c1.x, c1.y);
            if (f1) recompute2x2(A, B, r0, c0i + 2, c0.z, c0.w, c1.z, c1.w);
        }
        *(float4*)(out + rowbase + (size_t)(2 * a) * NCOL)     = c0;
        *(float4*)(out + rowbase + (size_t)(2 * a + 1) * NCOL) = c1;
    }
}

extern "C" void kernel_launch(void* const* d_in, const int* in_sizes, int n_in,
                              void* d_out, int out_size, void* d_ws, size_t ws_size,
                              hipStream_t stream) {
    const float* A = (const float*)d_in[0];   // (8192, 64)
    const float* B = (const float*)d_in[1];   // (8192, 64)
    const float* C = (const float*)d_in[2];   // (8192, 8192) faulty
    float* out = (float*)d_out;               // (8192, 8192)
    dim3 grid(NCOL / COLS, NCOL / ROWS);      // 32 x 256; x-fastest = adjacent
    correct_kernel<<<grid, 256, 0, stream>>>(A, B, C, out);   // col segments
}

// Round 8
// 118.240 us; speedup vs baseline: 1.2753x; 1.1387x over previous
//
#include <hip/hip_runtime.h>

// Correction_Module_dense_checksum: ABFT 2x2 block checksum verify + correct.
// A: (8192, 64) f32, B: (8192, 64) f32, C_faulty: (8192, 8192) f32 -> out f32.
// check[i][j] = (B[2i]+B[2i+1]) . (A[2j]+A[2j+1]); actual = 2x2 block sum of C.
// Flag iff |actual - check| > ATOL + RTOL*|check|; flagged blocks recomputed
// as B[r].A[c]. Fault margin ~100 vs tol ~1e-3 -> mask reproduction-robust.
//
// R8: strip pipeline, debugged. R6's test was void (spills: cvA+cvB=64 regs
// vs 64-VGPR budget). Now strip=16 rows (cv dbuf = 32 regs), launch_bounds
// (256,2) so the allocator can take ~100 regs without spilling; LDS 36KB
// still -> 4 blocks/CU at <=128 VGPR. Block owns 256x256 panel: AC staged
// once (reused 16x), per strip only 2KB BC restage (dbuf'd) + C loads that
// fly during the previous strip's dot loop. nt stores (R7 A/B: +25us).

constexpr int   Ddim   = 64;
constexpr int   NCOL   = 8192;
constexpr int   COLS   = 256;   // cols per block (128 j-blocks)
constexpr int   SROWS  = 16;    // rows per strip (8 i-blocks)
constexpr int   NSTRIP = 16;    // strips per block (256 rows)
constexpr float ATOL   = 1e-3f;
constexpr float RTOL   = 1e-4f;

typedef float vfloat4 __attribute__((ext_vector_type(4)));

__device__ __forceinline__ void nt_store4(float* p, float4 v) {
    vfloat4 w = {v.x, v.y, v.z, v.w};
    __builtin_nontemporal_store(w, (vfloat4*)p);
}

__device__ __forceinline__ void recompute2x2(const float* __restrict__ A,
                                             const float* __restrict__ B,
                                             int r0, int c0,
                                             float& e00, float& e01,
                                             float& e10, float& e11)
{
    const float* b0 = B + (size_t)r0 * Ddim;
    const float* b1 = b0 + Ddim;
    const float* a0 = A + (size_t)c0 * Ddim;
    const float* a1 = a0 + Ddim;
    float d00 = 0.f, d01 = 0.f, d10 = 0.f, d11 = 0.f;
    for (int d = 0; d < Ddim; ++d) {
        float bb0 = b0[d], bb1 = b1[d], aa0 = a0[d], aa1 = a1[d];
        d00 += bb0 * aa0;
        d01 += bb0 * aa1;
        d10 += bb1 * aa0;
        d11 += bb1 * aa1;
    }
    e00 = d00; e01 = d01; e10 = d10; e11 = d11;
}

__global__ __launch_bounds__(256, 2)
void correct_kernel(const float* __restrict__ A, const float* __restrict__ B,
                    const float* __restrict__ C, float* __restrict__ out)
{
    __shared__ float ACs[64][128];    // pair-summed A, staged once: 32 KiB
    __shared__ float BCs[2][64][8];   // pair-summed B per strip, dbuf: 4 KiB

    const int t  = threadIdx.x;
    const int bx = blockIdx.x;        // col panel (256 cols)
    const int gy = blockIdx.y;        // row panel (256 rows)
    const int w  = t >> 6;            // wave 0..3
    const int l  = t & 63;            // lane

    const int rowtop  = gy * (SROWS * NSTRIP);      // panel top row
    const size_t colbase = (size_t)(bx * COLS + 4 * l);

    // BC staging role (threads 0..127): 16 lanes cover one B row contiguous
    const bool bc_on = (t < 128);
    const int  dqB   = t & 15;        // d-quad: 64B contiguous per 16 lanes
    const int  ibB   = t >> 4;        // i-block within strip 0..7

    // ---- prologue: AC loads, BC(0) loads, cv(0) loads (vmcnt order) ----
    const int jj = t & 127;
    const int q  = t >> 7;
    const float* arow = A + (size_t)(bx * 128 + jj) * 2 * Ddim + q * 32;
    float4 sa0[8], sa1[8];
    #pragma unroll
    for (int i = 0; i < 8; ++i) {
        sa0[i] = *(const float4*)(arow + 4 * i);
        sa1[i] = *(const float4*)(arow + Ddim + 4 * i);
    }
    float4 nb0, nb1;
    if (bc_on) {
        const float* brow = B + (size_t)(rowtop + 2 * ibB) * Ddim + 4 * dqB;
        nb0 = *(const float4*)(brow);
        nb1 = *(const float4*)(brow + Ddim);
    }
    float4 cvA[4], cvB[4];
    {
        const float* p = C + (size_t)(rowtop + 4 * w) * NCOL + colbase;
        #pragma unroll
        for (int r = 0; r < 4; ++r)
            cvA[r] = *(const float4*)(p + (size_t)r * NCOL);
    }

    // ---- LDS writes (AC waits sa only; BC waits nb; cv stays in flight) ----
    #pragma unroll
    for (int i = 0; i < 8; ++i) {
        const int d0 = q * 32 + 4 * i;
        #pragma unroll
        for (int k = 0; k < 4; ++k)     // banks jj%32, 2 lanes/bank: free
            ACs[d0 + k][jj] = ((const float*)&sa0[i])[k] + ((const float*)&sa1[i])[k];
    }
    if (bc_on) {
        #pragma unroll
        for (int k = 0; k < 4; ++k)
            BCs[0][4 * dqB + k][ibB] = ((const float*)&nb0)[k] + ((const float*)&nb1)[k];
    }
    __syncthreads();

    // ---- strip loop: dot(s) runs while s+1's BC + C loads fly ----
#define STRIP_BODY(CV_CUR, CV_NXT, S, PF)                                        \
    {                                                                            \
        const int s = (S);                                                       \
        float4 pb0, pb1;                                                         \
        if (PF) {                                                                \
            if (bc_on) {                                                         \
                const float* brow = B + (size_t)(rowtop + (s + 1) * SROWS        \
                                                 + 2 * ibB) * Ddim + 4 * dqB;    \
                pb0 = *(const float4*)(brow);                                    \
                pb1 = *(const float4*)(brow + Ddim);                             \
            }                                                                    \
            const float* p = C + (size_t)(rowtop + (s + 1) * SROWS + 4 * w)      \
                                 * NCOL + colbase;                               \
            _Pragma("unroll")                                                    \
            for (int r = 0; r < 4; ++r)                                          \
                CV_NXT[r] = *(const float4*)(p + (size_t)r * NCOL);              \
        }                                                                        \
        float a00 = 0.f, a01 = 0.f, a10 = 0.f, a11 = 0.f;                        \
        const float (*bc)[8] = BCs[s & 1];                                       \
        _Pragma("unroll 16")                                                     \
        for (int d = 0; d < 64; ++d) {                                           \
            float2 b2 = *(const float2*)&bc[d][2 * w];    /* wave-uniform */     \
            float2 a2 = *(const float2*)&ACs[d][2 * l];   /* 512B/wave */        \
            a00 += b2.x * a2.x;  a01 += b2.x * a2.y;                             \
            a10 += b2.y * a2.x;  a11 += b2.y * a2.y;                             \
        }                                                                        \
        if (PF) {                                                                \
            if (bc_on) {                                                         \
                _Pragma("unroll")                                                \
                for (int k = 0; k < 4; ++k)                                      \
                    BCs[(s + 1) & 1][4 * dqB + k][ibB] =                         \
                        ((const float*)&pb0)[k] + ((const float*)&pb1)[k];       \
            }                                                                    \
            __syncthreads();                                                     \
        }                                                                        \
        const size_t rb = (size_t)(rowtop + s * SROWS + 4 * w) * NCOL + colbase; \
        {                                                                        \
            float4 c0 = CV_CUR[0], c1 = CV_CUR[1];                               \
            float4 c2 = CV_CUR[2], c3 = CV_CUR[3];                               \
            float s00 = (c0.x + c0.y) + (c1.x + c1.y);                           \
            float s01 = (c0.z + c0.w) + (c1.z + c1.w);                           \
            float s10 = (c2.x + c2.y) + (c3.x + c3.y);                           \
            float s11 = (c2.z + c2.w) + (c3.z + c3.w);                           \
            bool f00 = fabsf(s00 - a00) > ATOL + RTOL * fabsf(a00);              \
            bool f01 = fabsf(s01 - a01) > ATOL + RTOL * fabsf(a01);              \
            bool f10 = fabsf(s10 - a10) > ATOL + RTOL * fabsf(a10);              \
            bool f11 = fabsf(s11 - a11) > ATOL + RTOL * fabsf(a11);              \
            if (f00 | f01 | f10 | f11) {                                         \
                const int r0  = rowtop + s * SROWS + 4 * w;                      \
                const int c0i = (int)colbase;                                    \
                if (f00) recompute2x2(A, B, r0,     c0i,     c0.x, c0.y, c1.x, c1.y); \
                if (f01) recompute2x2(A, B, r0,     c0i + 2, c0.z, c0.w, c1.z, c1.w); \
                if (f10) recompute2x2(A, B, r0 + 2, c0i,     c2.x, c2.y, c3.x, c3.y); \
                if (f11) recompute2x2(A, B, r0 + 2, c0i + 2, c2.z, c2.w, c3.z, c3.w); \
            }                                                                    \
            nt_store4(out + rb,                    c0);                          \
            nt_store4(out + rb + (size_t)NCOL,     c1);                          \
            nt_store4(out + rb + (size_t)2 * NCOL, c2);                          \
            nt_store4(out + rb + (size_t)3 * NCOL, c3);                          \
        }                                                                        \
    }

    #pragma unroll 1
    for (int sp = 0; sp < NSTRIP / 2; ++sp) {
        STRIP_BODY(cvA, cvB, 2 * sp,     true);        // s+1 <= 15 always
        STRIP_BODY(cvB, cvA, 2 * sp + 1, (sp < NSTRIP / 2 - 1));
    }
#undef STRIP_BODY
}

extern "C" void kernel_launch(void* const* d_in, const int* in_sizes, int n_in,
                              void* d_out, int out_size, void* d_ws, size_t ws_size,
                              hipStream_t stream) {
    const float* A = (const float*)d_in[0];   // (8192, 64)
    const float* B = (const float*)d_in[1];   // (8192, 64)
    const float* C = (const float*)d_in[2];   // (8192, 8192) faulty
    float* out = (float*)d_out;               // (8192, 8192)
    dim3 grid(NCOL / COLS, NCOL / (SROWS * NSTRIP));   // 32 x 32 = 1024 blocks
    correct_kernel<<<grid, 256, 0, stream>>>(A, B, C, out);
}